// Round 5
// baseline (275.997 us; speedup 1.0000x reference)
//
#include <hip/hip_runtime.h>

// CapsuleNetwork routing, fused, one block per batch. B=2048, S=200, D=64, K=4.
//
// hat[b,k,s,:] = emb[b,s,:] @ W_k + b_k is never materialized:
//   logits[k,s] = emb[s]·u[k] + off[k],  u[k] = W_k @ G[k], off[k] = b_k·G[k]
//   v[k]        = e[k] @ W_k + ts[k]·b_k, e[k] = sum_s sw[k,s] emb[s]
// G = running sum of interests (cw telescopes).
//
// Round-5:
//  - MASK COMPACTION: masked rows have sw==0 exactly -> contribute nothing.
//    Stage only active rows (~100 of 200): halves B/D work, LDS 51.7KB ->
//    3 blocks/CU. Epilogue handles >CAP active rows from global (never fires
//    on this data, kept for correctness).
//  - Phase A + mini-reduce folded into E tail (same-wave LDS write->read
//    needs no barrier): 4 barriers/iter instead of 7.
//  - Phase B quarter-split (4 lanes per row) -> ~6.4 active waves.
//  - W read from L2 each use (no wreg cache) to keep VGPRs low.

#define NB 2048
#define NS 200
#define ND 64
#define NK 4
#define NT 512
#define CAP 140  // LDS-staged active rows (multiple of 4); semb padded +4 rows

__device__ __forceinline__ float wred64(float v) {
#pragma unroll
  for (int o = 1; o < 64; o <<= 1) v += __shfl_xor(v, o, 64);
  return v;
}

__device__ __forceinline__ void gload16(const float* g_, float* l_) {
  __builtin_amdgcn_global_load_lds(
      (const __attribute__((address_space(1))) unsigned int*)g_,
      (__attribute__((address_space(3))) unsigned int*)l_, 16, 0, 0);
}

#define RED_GRP(v) v += __shfl_xor(v, 16, 64); v += __shfl_xor(v, 32, 64);
#define RED_Q(v)   v += __shfl_xor(v, 1, 64);  v += __shfl_xor(v, 2, 64);

__global__ __launch_bounds__(NT, 6) void caps_kernel(
    const float* __restrict__ his, const float* __restrict__ itemeb,
    const int* __restrict__ mask, const float* __restrict__ W,
    const float* __restrict__ bias, float* __restrict__ out) {
  __shared__ float semb[(CAP + 4) * ND];  // 36864B: compact row i, chunk c at
                                          // slot (c+i)&15 (16B chunks)
  __shared__ float ssw4[NS * NK];         // sw[i][k] by compact index
  __shared__ float pe[8][NK][ND];         // per-wave D partials
  __shared__ float se[NK][ND];            // reduced e[k]
  __shared__ float pv[NK][ND];            // E h1 partials; final interest stash
  __shared__ float sG[NK][ND];            // running interest sum
  __shared__ float su[NK][ND];            // u[k]
  __shared__ unsigned short sidxs[NS];    // compact index -> original s
  __shared__ int swofs[8];
  __shared__ float pts[8][NK];
  __shared__ float soff[NK], satt[NK];
  __shared__ int sidx;

  const int t = threadIdx.x;
  const int w = t >> 6, l = t & 63;
  const int g = l >> 4, j = l & 15;  // 16-lane group / chunk
  const int gid = (w << 2) | g;      // 0..31
  const int k_ = w & 3, h_ = w >> 2;
  const int b = blockIdx.x;
  const float* eb = his + (size_t)b * NS * ND;

  // ---- compaction: active-row list via ballot prefix ----
  int m = (t < NS) ? (mask[b * NS + t] != 0) : 0;
  unsigned long long bal = __ballot(m);
  int pre = __popcll(bal & ((1ull << l) - 1));
  if (l == 0) swofs[w] = __popcll(bal);
  float breg = bias[k_ * ND + l];
  float iq = itemeb[(size_t)b * ND + l];
  __syncthreads();
  int base = 0;
#pragma unroll
  for (int ww = 0; ww < 8; ++ww) base += (ww < w) ? swofs[ww] : 0;
  if (m) sidxs[base + pre] = (unsigned short)t;
  int nact = 0;
#pragma unroll
  for (int ww = 0; ww < 8; ++ww) nact += swofs[ww];
  __syncthreads();
  const int ncore = nact < CAP ? nact : CAP;

  // ---- stage active rows (linear LDS dest, rotated global source) ----
  for (int i4 = w; 4 * i4 < ncore; i4 += 8) {
    int i = 4 * i4 + g;                      // dest compact row
    int ii = (i < ncore) ? i : (ncore - 1);  // clamp (dup tail, never read)
    int s = sidxs[ii];
    int qq = (j - i) & 15;  // global chunk that lands at slot j
    gload16(eb + (s << 6) + (qq << 2), &semb[i4 * 256]);
  }
  __syncthreads();

  for (int it = 0; it < 3; ++it) {
    if (it > 0) {
      // ---- B: quartet (4 lanes) per compact row; in-lane softmax ----
      const int qB = t & 3;
      for (int i = (t >> 2); i < ncore; i += 128) {
        float l0 = 0.f, l1 = 0.f, l2 = 0.f, l3 = 0.f;
#pragma unroll
        for (int c2 = 0; c2 < 4; ++c2) {
          int jj = qB * 4 + c2;
          float4 eq = *(const float4*)&semb[(i << 6) + 4 * ((jj + i) & 15)];
          float4 u0 = *(const float4*)&su[0][4 * jj];
          float4 u1 = *(const float4*)&su[1][4 * jj];
          float4 u2 = *(const float4*)&su[2][4 * jj];
          float4 u3 = *(const float4*)&su[3][4 * jj];
          l0 += eq.x * u0.x + eq.y * u0.y + eq.z * u0.z + eq.w * u0.w;
          l1 += eq.x * u1.x + eq.y * u1.y + eq.z * u1.z + eq.w * u1.w;
          l2 += eq.x * u2.x + eq.y * u2.y + eq.z * u2.z + eq.w * u2.w;
          l3 += eq.x * u3.x + eq.y * u3.y + eq.z * u3.z + eq.w * u3.w;
        }
        RED_Q(l0) RED_Q(l1) RED_Q(l2) RED_Q(l3)
        l0 += soff[0]; l1 += soff[1]; l2 += soff[2]; l3 += soff[3];
        float mx = fmaxf(fmaxf(l0, l1), fmaxf(l2, l3));
        float e0 = __expf(l0 - mx), e1 = __expf(l1 - mx);
        float e2 = __expf(l2 - mx), e3 = __expf(l3 - mx);
        float r = 1.0f / (e0 + e1 + e2 + e3);
        if (qB == 0)
          *(float4*)&ssw4[i * 4] = make_float4(e0 * r, e1 * r, e2 * r, e3 * r);
      }
      // rare epilogue: active rows beyond CAP, straight from global
      for (int i = CAP + t; i < nact; i += NT) {
        int s = sidxs[i];
        const float4* er = (const float4*)(eb + (s << 6));
        float l0 = soff[0], l1 = soff[1], l2 = soff[2], l3 = soff[3];
#pragma unroll
        for (int jj = 0; jj < 16; ++jj) {
          float4 eq = er[jj];
          float4 u0 = *(const float4*)&su[0][4 * jj];
          float4 u1 = *(const float4*)&su[1][4 * jj];
          float4 u2 = *(const float4*)&su[2][4 * jj];
          float4 u3 = *(const float4*)&su[3][4 * jj];
          l0 += eq.x * u0.x + eq.y * u0.y + eq.z * u0.z + eq.w * u0.w;
          l1 += eq.x * u1.x + eq.y * u1.y + eq.z * u1.z + eq.w * u1.w;
          l2 += eq.x * u2.x + eq.y * u2.y + eq.z * u2.z + eq.w * u2.w;
          l3 += eq.x * u3.x + eq.y * u3.y + eq.z * u3.z + eq.w * u3.w;
        }
        float mx = fmaxf(fmaxf(l0, l1), fmaxf(l2, l3));
        float e0 = __expf(l0 - mx), e1 = __expf(l1 - mx);
        float e2 = __expf(l2 - mx), e3 = __expf(l3 - mx);
        float r = 1.0f / (e0 + e1 + e2 + e3);
        *(float4*)&ssw4[i * 4] = make_float4(e0 * r, e1 * r, e2 * r, e3 * r);
      }
      __syncthreads();
    }

    // ---- D: group gid sweeps compact rows i = gid + 32t ----
    float4 a0 = {0, 0, 0, 0}, a1 = {0, 0, 0, 0}, a2 = {0, 0, 0, 0},
           a3 = {0, 0, 0, 0};
    float t0 = 0, t1 = 0, t2 = 0, t3 = 0;
    for (int i = gid; i < ncore; i += 32) {
      float4 eq = *(const float4*)&semb[(i << 6) + 4 * ((j + i) & 15)];
      if (it == 0) {
        a0.x += eq.x; a0.y += eq.y; a0.z += eq.z; a0.w += eq.w;
        t0 += 1.0f;
      } else {
        float4 s4 = *(const float4*)&ssw4[i * 4];  // broadcast
        a0.x += s4.x * eq.x; a0.y += s4.x * eq.y; a0.z += s4.x * eq.z; a0.w += s4.x * eq.w;
        a1.x += s4.y * eq.x; a1.y += s4.y * eq.y; a1.z += s4.y * eq.z; a1.w += s4.y * eq.w;
        a2.x += s4.z * eq.x; a2.y += s4.z * eq.y; a2.z += s4.z * eq.z; a2.w += s4.z * eq.w;
        a3.x += s4.w * eq.x; a3.y += s4.w * eq.y; a3.z += s4.w * eq.z; a3.w += s4.w * eq.w;
        t0 += s4.x; t1 += s4.y; t2 += s4.z; t3 += s4.w;
      }
    }
    // rare epilogue rows from global (unswizzled chunk j)
    for (int i = CAP + gid; i < nact; i += 32) {
      int s = sidxs[i];
      float4 eq = *(const float4*)&eb[(s << 6) + 4 * j];
      if (it == 0) {
        a0.x += eq.x; a0.y += eq.y; a0.z += eq.z; a0.w += eq.w;
        t0 += 1.0f;
      } else {
        float4 s4 = *(const float4*)&ssw4[i * 4];
        a0.x += s4.x * eq.x; a0.y += s4.x * eq.y; a0.z += s4.x * eq.z; a0.w += s4.x * eq.w;
        a1.x += s4.y * eq.x; a1.y += s4.y * eq.y; a1.z += s4.y * eq.z; a1.w += s4.y * eq.w;
        a2.x += s4.z * eq.x; a2.y += s4.z * eq.y; a2.z += s4.z * eq.z; a2.w += s4.z * eq.w;
        a3.x += s4.w * eq.x; a3.y += s4.w * eq.y; a3.z += s4.w * eq.z; a3.w += s4.w * eq.w;
        t0 += s4.x; t1 += s4.y; t2 += s4.z; t3 += s4.w;
      }
    }
    RED_GRP(a0.x) RED_GRP(a0.y) RED_GRP(a0.z) RED_GRP(a0.w) RED_GRP(t0)
    if (it > 0) {
      RED_GRP(a1.x) RED_GRP(a1.y) RED_GRP(a1.z) RED_GRP(a1.w)
      RED_GRP(a2.x) RED_GRP(a2.y) RED_GRP(a2.z) RED_GRP(a2.w)
      RED_GRP(a3.x) RED_GRP(a3.y) RED_GRP(a3.z) RED_GRP(a3.w)
      RED_GRP(t1) RED_GRP(t2) RED_GRP(t3)
    } else {
      a0.x *= 0.25f; a0.y *= 0.25f; a0.z *= 0.25f; a0.w *= 0.25f;
      t0 *= 0.25f;
      a1 = a0; a2 = a0; a3 = a0; t1 = t0; t2 = t0; t3 = t0;
    }
    if (l < 16) {
      *(float4*)&pe[w][0][4 * l] = a0;
      *(float4*)&pe[w][1][4 * l] = a1;
      *(float4*)&pe[w][2][4 * l] = a2;
      *(float4*)&pe[w][3][4 * l] = a3;
    }
    if (l == 0) { pts[w][0] = t0; pts[w][1] = t1; pts[w][2] = t2; pts[w][3] = t3; }
    __syncthreads();

    // ---- E1: wave (k,h): reduce pe half, dot with W columns (L2-hot) ----
    {
      int cl = 32 * h_ + (l & 31);
      float sse = 0.f;
#pragma unroll
      for (int w2 = 0; w2 < 8; ++w2) sse += pe[w2][k_][cl];
      se[k_][cl] = sse;  // same-wave write->read below (no barrier needed)
      float vp = 0.f;
      const float* Wc = W + k_ * ND + l;
#pragma unroll
      for (int q2 = 0; q2 < 8; ++q2) {
        int c = 32 * h_ + 4 * q2;
        float4 e4 = *(const float4*)&se[k_][c];  // broadcast
        vp += e4.x * Wc[(size_t)(c + 0) * (NK * ND)];
        vp += e4.y * Wc[(size_t)(c + 1) * (NK * ND)];
        vp += e4.z * Wc[(size_t)(c + 2) * (NK * ND)];
        vp += e4.w * Wc[(size_t)(c + 3) * (NK * ND)];
      }
      if (h_) pv[k_][l] = vp;
      __syncthreads();

      // ---- E2 (waves 0-3): combine, squash, update G, fold in phase A ----
      if (h_ == 0) {
        float ts_ = 0.f;
#pragma unroll
        for (int w2 = 0; w2 < 8; ++w2) ts_ += pts[w2][k_];
        float accv = vp + pv[k_][l] + ts_ * breg;
        float n2 = wred64(accv * accv);
        float scale = n2 / (1.f + n2) / sqrtf(n2 + 1e-9f);
        float inter = scale * accv;
        if (it < 2) {
          float gnew = (it == 0) ? inter : (sG[k_][l] + inter);
          sG[k_][l] = gnew;  // same-wave reuse below
          float ob = wred64(breg * gnew);
          if (l == 0) soff[k_] = ob;
          // phase-A merge: su[k][l] = W-row l (cols 64k..) dot G[k]
          const float4* Wr = (const float4*)(W + (size_t)l * (NK * ND) + k_ * ND);
          const float4* Gk = (const float4*)&sG[k_][0];  // broadcast
          float a = 0.f;
#pragma unroll
          for (int d4 = 0; d4 < 16; ++d4) {
            float4 wv = Wr[d4], gv = Gk[d4];
            a += wv.x * gv.x + wv.y * gv.y + wv.z * gv.z + wv.w * gv.w;
          }
          su[k_][l] = a;
        } else {
          out[((size_t)b * NK + k_) * ND + l] = inter;
          float dot_ = wred64(inter * iq);
          pv[k_][l] = inter;  // stash for argmax gather
          if (l == 0) satt[k_] = dot_;
        }
      }
      __syncthreads();
    }
  }

  // ---- readout: first-max argmax (== np.argmax) + gather ----
  if (t == 0) {
    int bi = 0;
    float bv = satt[0];
#pragma unroll
    for (int kk = 1; kk < NK; ++kk)
      if (satt[kk] > bv) { bv = satt[kk]; bi = kk; }
    sidx = bi;
  }
  __syncthreads();
  if (t < ND) out[(size_t)NB * NK * ND + (size_t)b * ND + t] = pv[sidx][t];
}

extern "C" void kernel_launch(void* const* d_in, const int* in_sizes, int n_in,
                              void* d_out, int out_size, void* d_ws, size_t ws_size,
                              hipStream_t stream) {
  (void)in_sizes; (void)n_in; (void)out_size; (void)d_ws; (void)ws_size;
  const float* his = (const float*)d_in[0];
  const float* itemeb = (const float*)d_in[1];
  const int* mask = (const int*)d_in[2];
  const float* W = (const float*)d_in[3];
  const float* bias = (const float*)d_in[4];
  float* out = (float*)d_out;
  caps_kernel<<<NB, NT, 0, stream>>>(his, itemeb, mask, W, bias, out);
}